// Round 16
// baseline (184.043 us; speedup 1.0000x reference)
//
#include <hip/hip_runtime.h>

// Problem constants (B=4, L=2048, C=512, H=8, D=64)
#define CDIM 512
#define LDIM 2048
#define BDIM 4
#define HDIM 8
#define DDIM 64

typedef __attribute__((ext_vector_type(8))) short bf16x8;
typedef __attribute__((ext_vector_type(4))) float f32x4;
typedef __attribute__((ext_vector_type(2))) float f32x2;
typedef __attribute__((ext_vector_type(8))) unsigned short ushort8;

static __device__ __forceinline__ unsigned short f2bf(float f) {
  unsigned u = __float_as_uint(f);
  return (unsigned short)((u + 0x7FFFu + ((u >> 16) & 1u)) >> 16);
}

// ---------------------------------------------------------------------------
// Kernel 0: fp32 -> bf16 convert of x (4194304), qkv_w (786432), proj_w
// (262144). 8 floats/thread, exact grid (5242880/8/256 = 2560 blocks).
// ---------------------------------------------------------------------------
__global__ __launch_bounds__(256) void convert_kernel(
    const float* __restrict__ x, const float* __restrict__ qw,
    const float* __restrict__ pw, unsigned short* __restrict__ xb,
    unsigned short* __restrict__ wb, unsigned short* __restrict__ pwb) {
  const size_t i = ((size_t)blockIdx.x * 256 + threadIdx.x) * 8;
  const float* src; unsigned short* dst; size_t off;
  if (i < 4194304) { src = x;  dst = xb;  off = i; }
  else if (i < 4980736) { src = qw; dst = wb;  off = i - 4194304; }
  else { src = pw; dst = pwb; off = i - 4980736; }
  const float4 a = *(const float4*)(src + off);
  const float4 b = *(const float4*)(src + off + 4);
  ushort8 h;
  h[0] = f2bf(a.x); h[1] = f2bf(a.y); h[2] = f2bf(a.z); h[3] = f2bf(a.w);
  h[4] = f2bf(b.x); h[5] = f2bf(b.y); h[6] = f2bf(b.z); h[7] = f2bf(b.w);
  *(ushort8*)(dst + off) = h;
}

// ---------------------------------------------------------------------------
// Kernel 1: qkv = x @ qkv_w^T + b via bf16 MFMA, fused RoPE epilogue.
// XCD-swizzled 1D grid (768). (verbatim round 13, verified)
// ---------------------------------------------------------------------------
__global__ __launch_bounds__(256) void qkv_gemm_kernel(
    const unsigned short* __restrict__ xb, const unsigned short* __restrict__ wb,
    const float* __restrict__ bias, const float* __restrict__ cosT,
    const float* __restrict__ sinT, unsigned short* __restrict__ qb,
    unsigned short* __restrict__ kb, unsigned short* __restrict__ vt) {
  __shared__ char As[16384];
  __shared__ char Bs[16384];
  const int t  = threadIdx.x;
  const int w  = t >> 6, lane = t & 63;
  const int lo = lane & 15, hi = lane >> 4;
  const int wm = w >> 1, wn = w & 1;
  const int flat = blockIdx.x;
  const int xcd = flat & 7, j = flat >> 3;          // j in 0..95
  const int m0 = (xcd + 8 * (j / 12)) * 128;
  const int n0 = (j % 12) * 128;

  f32x4 acc[4][4];
  #pragma unroll
  for (int mt = 0; mt < 4; ++mt)
    #pragma unroll
    for (int nt = 0; nt < 4; ++nt) acc[mt][nt] = (f32x4){0.f, 0.f, 0.f, 0.f};

  const int srow   = t >> 3;
  const int schunk = ((t & 7) ^ (srow & 7)) << 4;
  const char* Ag = (const char*)xb;
  const char* Bg = (const char*)wb;

  for (int kt = 0; kt < CDIM; kt += 64) {
    #pragma unroll
    for (int s = 0; s < 4; ++s) {
      const int r = s * 32 + srow;
      __builtin_amdgcn_global_load_lds(
          (const __attribute__((address_space(1))) unsigned int*)
              (Ag + (size_t)(m0 + r) * 1024 + kt * 2 + schunk),
          (__attribute__((address_space(3))) unsigned int*)(As + s * 4096 + w * 1024),
          16, 0, 0);
      __builtin_amdgcn_global_load_lds(
          (const __attribute__((address_space(1))) unsigned int*)
              (Bg + (size_t)(n0 + r) * 1024 + kt * 2 + schunk),
          (__attribute__((address_space(3))) unsigned int*)(Bs + s * 4096 + w * 1024),
          16, 0, 0);
    }
    __syncthreads();
    #pragma unroll
    for (int ks = 0; ks < 2; ++ks) {
      bf16x8 af[4], bfr[4];
      #pragma unroll
      for (int mt = 0; mt < 4; ++mt)
        af[mt] = *(const bf16x8*)(As + (wm * 64 + mt * 16 + lo) * 128
                                  + (((ks * 4 + hi) ^ (lo & 7)) << 4));
      #pragma unroll
      for (int nt = 0; nt < 4; ++nt)
        bfr[nt] = *(const bf16x8*)(Bs + (wn * 64 + nt * 16 + lo) * 128
                                   + (((ks * 4 + hi) ^ (lo & 7)) << 4));
      #pragma unroll
      for (int mt = 0; mt < 4; ++mt)
        #pragma unroll
        for (int nt = 0; nt < 4; ++nt)
          acc[mt][nt] = __builtin_amdgcn_mfma_f32_16x16x32_bf16(
              af[mt], bfr[nt], acc[mt][nt], 0, 0, 0);
    }
    __syncthreads();
  }

  const int nbase = n0 + wn * 64;
  const int typ   = nbase >> 9;
  const int hh    = (nbase >> 6) & 7;
  const int bb    = m0 >> 11;
  const int lbase = (m0 & 2047) + wm * 64;

  float bq[4];
  #pragma unroll
  for (int nt = 0; nt < 4; ++nt) bq[nt] = bias[nbase + nt * 16 + lo];
  #pragma unroll
  for (int mt = 0; mt < 4; ++mt)
    #pragma unroll
    for (int nt = 0; nt < 4; ++nt)
      #pragma unroll
      for (int reg = 0; reg < 4; ++reg) acc[mt][nt][reg] += bq[nt];

  if (typ == 2) {
    unsigned short* vbase = vt + (size_t)(bb * HDIM + hh) * DDIM * LDIM;
    #pragma unroll
    for (int mt = 0; mt < 4; ++mt)
      #pragma unroll
      for (int nt = 0; nt < 4; ++nt) {
        const int d = nt * 16 + lo;
        #pragma unroll
        for (int reg = 0; reg < 4; ++reg) {
          const int l = lbase + mt * 16 + hi * 4 + reg;
          vbase[(size_t)d * LDIM + l] = f2bf(acc[mt][nt][reg]);
        }
      }
  } else {
    unsigned short* dstb = (typ ? kb : qb) + (size_t)(bb * HDIM + hh) * LDIM * DDIM;
    #pragma unroll
    for (int mt = 0; mt < 4; ++mt)
      #pragma unroll
      for (int nt = 0; nt < 4; ++nt) {
        const int d   = nt * 16 + lo;
        const float sgn = (nt & 2) ? 1.f : -1.f;
        #pragma unroll
        for (int reg = 0; reg < 4; ++reg) {
          const int l = lbase + mt * 16 + hi * 4 + reg;
          const float c = cosT[l * 64 + d], s = sinT[l * 64 + d];
          const float v = acc[mt][nt][reg] * c + sgn * acc[mt][nt ^ 2][reg] * s;
          dstb[(size_t)l * DDIM + d] = f2bf(v);
        }
      }
  }
}

// ---------------------------------------------------------------------------
// Kernel 2: bf16 MFMA flash attention, barrier-free direct-L2 variant.
// KV is L2-resident (round-13 FETCH = 12.4MB @408GB/s), so K/V LDS staging
// was pure overhead (guide Common-mistake #7). K and V fragments are read
// DIRECTLY from global (same addresses the stage lambda used pre-swizzle;
// 16B/lane in 64B segments). LDS holds only the per-wave-private P tile ->
// ZERO barriers in the main loop. Block = 4 waves (2 q-waves x 2 KV-halves),
// grid 1024, XCD-swizzled (4 bh per XCD = 2MB KV in 4MB L2). vf loads hoisted
// above softmax to hide L2 latency under VALU. Softmax/fragments/epilogue
// math verbatim round 15 (verified, absmax 1.22e-4).
// ---------------------------------------------------------------------------
#define CLOG2 0.18033688f          /* 0.125 * log2(e) */

__global__ __launch_bounds__(256, 5) void attn_kernel(
    unsigned short* __restrict__ qb, const unsigned short* __restrict__ kb,
    const unsigned short* __restrict__ vt) {
  __shared__ char Lds[16896];
  // P: w*4096 in [0,16K)  (per-wave private)
  // epilogue alias: O at wq*8192 in [0,16K); l/m at 16384 + wq*256
  const int t    = threadIdx.x;
  const int w    = t >> 6, lane = t & 63;
  const int lo   = lane & 15, hi = lane >> 4;
  const int wq   = w & 1, half = w >> 1;
  const int flat = blockIdx.x;
  const int xcd  = flat & 7, jj = flat >> 3;        // jj in 0..127
  const int bh   = xcd + 8 * (jj >> 5);             // 32 bh, 4 per XCD
  const int q0   = (jj & 31) * 64 + wq * 32;
  const int kb0  = half * 1024;

  const char* Kb = (const char*)kb + (size_t)bh * (LDIM * DDIM * 2);
  const char* Vb = (const char*)vt + (size_t)bh * (LDIM * DDIM * 2);
  unsigned short* Qb = qb + (size_t)bh * (LDIM * DDIM);

  bf16x8 qf[2][2];
  #pragma unroll
  for (int g = 0; g < 2; ++g)
    #pragma unroll
    for (int kd = 0; kd < 2; ++kd)
      qf[g][kd] = *(const bf16x8*)((const char*)(Qb + (size_t)(q0 + g * 16 + lo) * DDIM)
                                   + kd * 64 + hi * 16);

  f32x4 o[2][4];
  float mrun[2] = {0.f, 0.f}, mc[2] = {0.f, 0.f}, lpart[2] = {0.f, 0.f};
  #pragma unroll
  for (int g = 0; g < 2; ++g)
    #pragma unroll
    for (int r = 0; r < 4; ++r) o[g][r] = (f32x4){0.f, 0.f, 0.f, 0.f};

  char* Pwb = Lds + w * 4096;

  for (int kt = 0; kt < 32; ++kt) {
    const int kbase = kb0 + kt * 32;

    // ---- S^T = K Q : kf direct from global/L2 ----
    f32x4 sv[2][2];
    __builtin_amdgcn_s_setprio(1);
    #pragma unroll
    for (int nt = 0; nt < 2; ++nt) {
      sv[0][nt] = (f32x4){0.f, 0.f, 0.f, 0.f};
      sv[1][nt] = (f32x4){0.f, 0.f, 0.f, 0.f};
      const int key = kbase + nt * 16 + lo;
      #pragma unroll
      for (int kd = 0; kd < 2; ++kd) {
        const bf16x8 kf = *(const bf16x8*)(Kb + (size_t)key * 128 + (kd * 4 + hi) * 16);
        sv[0][nt] = __builtin_amdgcn_mfma_f32_16x16x32_bf16(kf, qf[0][kd], sv[0][nt], 0, 0, 0);
        sv[1][nt] = __builtin_amdgcn_mfma_f32_16x16x32_bf16(kf, qf[1][kd], sv[1][nt], 0, 0, 0);
      }
    }
    __builtin_amdgcn_s_setprio(0);

    // ---- vf direct from global/L2, issued early (hidden under softmax) ----
    bf16x8 vf[4];
    #pragma unroll
    for (int dt = 0; dt < 4; ++dt) {
      const int d = dt * 16 + lo;
      vf[dt] = *(const bf16x8*)(Vb + (size_t)d * (LDIM * 2)
                                + (size_t)(kbase + hi * 8) * 2);
    }

    // ---- softmax per group: no max pass; pk_fma + raw v_exp_f32 ----
    #pragma unroll
    for (int g = 0; g < 2; ++g) {
      const float* sflat = (const float*)sv[g];
      const f32x2 cc2 = {CLOG2, CLOG2};
      const f32x2 mm2 = {-mc[g], -mc[g]};
      float pv[8];
      float ps = 0.f;
      #pragma unroll
      for (int i = 0; i < 4; ++i) {
        f32x2 a; a[0] = sflat[2*i]; a[1] = sflat[2*i+1];
        f32x2 xr;
        asm("v_pk_fma_f32 %0, %1, %2, %3" : "=v"(xr) : "v"(a), "v"(cc2), "v"(mm2));
        float p0, p1;
        asm("v_exp_f32 %0, %1" : "=v"(p0) : "v"(xr[0]));
        asm("v_exp_f32 %0, %1" : "=v"(p1) : "v"(xr[1]));
        pv[2*i] = p0; pv[2*i+1] = p1;
        ps += p0; ps += p1;
      }

      if (__builtin_expect((bool)__ballot(ps > 65536.f), 0)) {
        float mx = -1e30f;
        #pragma unroll
        for (int i = 0; i < 8; ++i) mx = fmaxf(mx, sflat[i]);
        mx = fmaxf(mx, __shfl_xor(mx, 16));
        mx = fmaxf(mx, __shfl_xor(mx, 32));
        const float newm = fmaxf(mrun[g], mx);
        const float al   = exp2f((mrun[g] - newm) * CLOG2);
        lpart[g] *= al;
        #pragma unroll
        for (int r = 0; r < 4; ++r) {
          const float aq = __shfl(al, (hi << 2) + r);
          #pragma unroll
          for (int dt = 0; dt < 4; ++dt) o[g][dt][r] *= aq;
        }
        mrun[g] = newm;
        mc[g]   = newm * CLOG2;
        ps = 0.f;
        #pragma unroll
        for (int i = 0; i < 8; ++i) {
          const float p = exp2f(fmaf(sflat[i], CLOG2, -mc[g]));
          pv[i] = p;
          ps += p;
        }
      }
      lpart[g] += ps;

      #pragma unroll
      for (int nt = 0; nt < 2; ++nt) {
        unsigned w0, w1;
        asm("v_cvt_pk_bf16_f32 %0, %1, %2"
            : "=v"(w0) : "v"(pv[nt*4+0]), "v"(pv[nt*4+1]));
        asm("v_cvt_pk_bf16_f32 %0, %1, %2"
            : "=v"(w1) : "v"(pv[nt*4+2]), "v"(pv[nt*4+3]));
        uint2 d2; d2.x = w0; d2.y = w1;
        *(uint2*)(Pwb + g * 2048 + lo * 128
                  + ((nt * 32 + hi * 8) ^ ((lo & 7) << 4))) = d2;
      }
    }

    // ---- O += P V (P via per-wave LDS; vf already in registers) ----
    __builtin_amdgcn_s_setprio(1);
    {
      const bf16x8 pf0 = *(const bf16x8*)(Pwb + lo * 128
                           + ((hi ^ (lo & 7)) << 4));
      const bf16x8 pf1 = *(const bf16x8*)(Pwb + 2048 + lo * 128
                           + ((hi ^ (lo & 7)) << 4));
      #pragma unroll
      for (int dt = 0; dt < 4; ++dt) {
        o[0][dt] = __builtin_amdgcn_mfma_f32_16x16x32_bf16(pf0, vf[dt], o[0][dt], 0, 0, 0);
        o[1][dt] = __builtin_amdgcn_mfma_f32_16x16x32_bf16(pf1, vf[dt], o[1][dt], 0, 0, 0);
      }
    }
    __builtin_amdgcn_s_setprio(0);
  }

  // ---- epilogue: merge halves through LDS (aliases P after syncthreads) ----
  __syncthreads();

  float rs[2];
  #pragma unroll
  for (int g = 0; g < 2; ++g) {
    rs[g] = lpart[g];
    rs[g] += __shfl_xor(rs[g], 16);
    rs[g] += __shfl_xor(rs[g], 32);
  }

  if (half == 1) {
    #pragma unroll
    for (int g = 0; g < 2; ++g) {
      #pragma unroll
      for (int dt = 0; dt < 4; ++dt)
        #pragma unroll
        for (int r = 0; r < 4; ++r)
          *(float*)(Lds + wq * 8192
                    + ((g * 16 + hi * 4 + r) * 64 + dt * 16 + lo) * 4) = o[g][dt][r];
      if (hi == 0) {
        *(float*)(Lds + 16384 + wq * 256 + g * 64 + lo * 4)       = rs[g];
        *(float*)(Lds + 16384 + wq * 256 + 128 + g * 64 + lo * 4) = mrun[g];
      }
    }
  }
  __syncthreads();
  if (half == 0) {
    #pragma unroll
    for (int g = 0; g < 2; ++g)
      #pragma unroll
      for (int r = 0; r < 4; ++r) {
        const int qrow = hi * 4 + r;
        const float m_a = __shfl(mrun[g], qrow);
        const float l_a = __shfl(rs[g], qrow);
        const float l_b = *(const float*)(Lds + 16384 + wq * 256 + g * 64 + qrow * 4);
        const float m_b = *(const float*)(Lds + 16384 + wq * 256 + 128 + g * 64 + qrow * 4);
        const float m  = fmaxf(m_a, m_b);
        const float aa = exp2f((m_a - m) * CLOG2);
        const float ab = exp2f((m_b - m) * CLOG2);
        const float inv = 1.f / (l_a * aa + l_b * ab);
        const int q = q0 + g * 16 + qrow;
        #pragma unroll
        for (int dt = 0; dt < 4; ++dt) {
          const float ob = *(const float*)(Lds + wq * 8192
                            + ((g * 16 + qrow) * 64 + dt * 16 + lo) * 4);
          Qb[(size_t)q * DDIM + dt * 16 + lo] =
              f2bf((o[g][dt][r] * aa + ob * ab) * inv);
        }
      }
  }
}

// ---------------------------------------------------------------------------
// Kernel 3: out = attn_out @ proj_w^T + b via bf16 MFMA. 64x128 tile,
// XCD-swizzled 1D grid (512). (verbatim round 13, verified)
// ---------------------------------------------------------------------------
__global__ __launch_bounds__(256) void proj_gemm_kernel(
    const unsigned short* __restrict__ ab, const unsigned short* __restrict__ pwb,
    const float* __restrict__ bias, float* __restrict__ out) {
  __shared__ char As[8192];
  __shared__ char Bs[16384];
  const int t  = threadIdx.x;
  const int w  = t >> 6, lane = t & 63;
  const int lo = lane & 15, hi = lane >> 4;
  const int wm = w >> 1, wn = w & 1;
  const int flat = blockIdx.x;
  const int xcd = flat & 7, j = flat >> 3;          // j in 0..63
  const int m0 = (xcd + 8 * (j >> 2)) * 64;
  const int n0 = (j & 3) * 128;

  f32x4 acc[2][4];
  #pragma unroll
  for (int mt = 0; mt < 2; ++mt)
    #pragma unroll
    for (int nt = 0; nt < 4; ++nt) acc[mt][nt] = (f32x4){0.f, 0.f, 0.f, 0.f};

  const int srow   = t >> 3;
  const int schunk = ((t & 7) ^ (srow & 7)) << 4;
  const char* Ag = (const char*)ab;
  const char* Bg = (const char*)pwb;

  for (int kt = 0; kt < CDIM; kt += 64) {
    const int hh = kt >> 6;
    #pragma unroll
    for (int s = 0; s < 2; ++s) {
      const int r = s * 32 + srow;
      const int m = m0 + r;
      const int bb = m >> 11, l = m & 2047;
      __builtin_amdgcn_global_load_lds(
          (const __attribute__((address_space(1))) unsigned int*)
              (Ag + ((size_t)(bb * HDIM + hh) * LDIM + l) * 128 + schunk),
          (__attribute__((address_space(3))) unsigned int*)(As + s * 4096 + w * 1024),
          16, 0, 0);
    }
    #pragma unroll
    for (int s = 0; s < 4; ++s) {
      const int r = s * 32 + srow;
      __builtin_amdgcn_global_load_lds(
          (const __attribute__((address_space(1))) unsigned int*)
              (Bg + (size_t)(n0 + r) * 1024 + kt * 2 + schunk),
          (__attribute__((address_space(3))) unsigned int*)(Bs + s * 4096 + w * 1024),
          16, 0, 0);
    }
    __syncthreads();
    #pragma unroll
    for (int ks = 0; ks < 2; ++ks) {
      bf16x8 af[2], bfr[4];
      #pragma unroll
      for (int mt = 0; mt < 2; ++mt)
        af[mt] = *(const bf16x8*)(As + (wm * 32 + mt * 16 + lo) * 128
                                  + (((ks * 4 + hi) ^ (lo & 7)) << 4));
      #pragma unroll
      for (int nt = 0; nt < 4; ++nt)
        bfr[nt] = *(const bf16x8*)(Bs + (wn * 64 + nt * 16 + lo) * 128
                                   + (((ks * 4 + hi) ^ (lo & 7)) << 4));
      #pragma unroll
      for (int mt = 0; mt < 2; ++mt)
        #pragma unroll
        for (int nt = 0; nt < 4; ++nt)
          acc[mt][nt] = __builtin_amdgcn_mfma_f32_16x16x32_bf16(
              af[mt], bfr[nt], acc[mt][nt], 0, 0, 0);
    }
    __syncthreads();
  }

  const int nn = n0 + wn * 64;
  float bp[4];
  #pragma unroll
  for (int nt = 0; nt < 4; ++nt) bp[nt] = bias[nn + nt * 16 + lo];
  #pragma unroll
  for (int mt = 0; mt < 2; ++mt)
    #pragma unroll
    for (int nt = 0; nt < 4; ++nt)
      #pragma unroll
      for (int reg = 0; reg < 4; ++reg) {
        const int m = m0 + wm * 32 + mt * 16 + hi * 4 + reg;
        out[(size_t)m * CDIM + nn + nt * 16 + lo] = acc[mt][nt][reg] + bp[nt];
      }
}

// ---------------------------------------------------------------------------
extern "C" void kernel_launch(void* const* d_in, const int* in_sizes, int n_in,
                              void* d_out, int out_size, void* d_ws, size_t ws_size,
                              hipStream_t stream) {
  const float* x      = (const float*)d_in[0];
  const float* qkv_w  = (const float*)d_in[1];
  const float* qkv_b  = (const float*)d_in[2];
  const float* proj_w = (const float*)d_in[3];
  const float* proj_b = (const float*)d_in[4];
  const float* cosT   = (const float*)d_in[5];
  const float* sinT   = (const float*)d_in[6];
  float* out = (float*)d_out;

  // ws layout (u16): qb 8MB | kb 8MB | vt 8MB | xb 8MB | wb 1.5MB | pwb 0.5MB
  unsigned short* qb  = (unsigned short*)d_ws;
  unsigned short* kb  = qb + (size_t)BDIM * HDIM * LDIM * DDIM;
  unsigned short* vt  = kb + (size_t)BDIM * HDIM * LDIM * DDIM;
  unsigned short* xb  = vt + (size_t)BDIM * HDIM * LDIM * DDIM;
  unsigned short* wb  = xb + (size_t)BDIM * LDIM * CDIM;
  unsigned short* pwb = wb + (size_t)3 * CDIM * CDIM;

  // 0) fp32 -> bf16 conversions (x + both weights)
  convert_kernel<<<dim3(2560), 256, 0, stream>>>(x, qkv_w, proj_w, xb, wb, pwb);
  // 1) QKV GEMM (bf16 MFMA) + fused RoPE + scatter (XCD-swizzled)
  qkv_gemm_kernel<<<dim3(768), 256, 0, stream>>>(xb, wb, qkv_b, cosT, sinT,
                                                 qb, kb, vt);
  // 2) bf16 MFMA flash attention (barrier-free, direct-L2 K/V, XCD-swizzled)
  attn_kernel<<<dim3(1024), 256, 0, stream>>>(qb, kb, vt);
  // 3) output projection (64x128 tile, XCD-swizzled)
  proj_gemm_kernel<<<dim3(512), 256, 0, stream>>>(qb, pwb, proj_b, out);
}

// Round 17
// 90.891 us; speedup vs baseline: 2.0249x; 2.0249x over previous
//
#include <hip/hip_runtime.h>

// Problem constants (B=4, L=2048, C=512, H=8, D=64)
#define CDIM 512
#define LDIM 2048
#define BDIM 4
#define HDIM 8
#define DDIM 64

typedef __attribute__((ext_vector_type(8))) short bf16x8;
typedef __attribute__((ext_vector_type(4))) float f32x4;
typedef __attribute__((ext_vector_type(2))) float f32x2;
typedef __attribute__((ext_vector_type(8))) unsigned short ushort8;

static __device__ __forceinline__ unsigned short f2bf(float f) {
  unsigned u = __float_as_uint(f);
  return (unsigned short)((u + 0x7FFFu + ((u >> 16) & 1u)) >> 16);
}

// ---------------------------------------------------------------------------
// Kernel 0: fp32 -> bf16 convert of x (4194304), qkv_w (786432), proj_w
// (262144). 8 floats/thread, exact grid (5242880/8/256 = 2560 blocks).
// ---------------------------------------------------------------------------
__global__ __launch_bounds__(256) void convert_kernel(
    const float* __restrict__ x, const float* __restrict__ qw,
    const float* __restrict__ pw, unsigned short* __restrict__ xb,
    unsigned short* __restrict__ wb, unsigned short* __restrict__ pwb) {
  const size_t i = ((size_t)blockIdx.x * 256 + threadIdx.x) * 8;
  const float* src; unsigned short* dst; size_t off;
  if (i < 4194304) { src = x;  dst = xb;  off = i; }
  else if (i < 4980736) { src = qw; dst = wb;  off = i - 4194304; }
  else { src = pw; dst = pwb; off = i - 4980736; }
  const float4 a = *(const float4*)(src + off);
  const float4 b = *(const float4*)(src + off + 4);
  ushort8 h;
  h[0] = f2bf(a.x); h[1] = f2bf(a.y); h[2] = f2bf(a.z); h[3] = f2bf(a.w);
  h[4] = f2bf(b.x); h[5] = f2bf(b.y); h[6] = f2bf(b.z); h[7] = f2bf(b.w);
  *(ushort8*)(dst + off) = h;
}

// ---------------------------------------------------------------------------
// Kernel 1: qkv = x @ qkv_w^T + b via bf16 MFMA, fused RoPE epilogue.
// XCD-swizzled 1D grid (768). NOW: double-buffered LDS + single-barrier loop
// (round-15 attn pattern: vmcnt(0); barrier; stage(next->buf^1); compute).
// ---------------------------------------------------------------------------
__global__ __launch_bounds__(256) void qkv_gemm_kernel(
    const unsigned short* __restrict__ xb, const unsigned short* __restrict__ wb,
    const float* __restrict__ bias, const float* __restrict__ cosT,
    const float* __restrict__ sinT, unsigned short* __restrict__ qb,
    unsigned short* __restrict__ kb, unsigned short* __restrict__ vt) {
  __shared__ char As[32768];   // 2 x 16KB
  __shared__ char Bs[32768];
  const int t  = threadIdx.x;
  const int w  = t >> 6, lane = t & 63;
  const int lo = lane & 15, hi = lane >> 4;
  const int wm = w >> 1, wn = w & 1;
  const int flat = blockIdx.x;
  const int xcd = flat & 7, j = flat >> 3;          // j in 0..95
  const int m0 = (xcd + 8 * (j / 12)) * 128;
  const int n0 = (j % 12) * 128;

  f32x4 acc[4][4];
  #pragma unroll
  for (int mt = 0; mt < 4; ++mt)
    #pragma unroll
    for (int nt = 0; nt < 4; ++nt) acc[mt][nt] = (f32x4){0.f, 0.f, 0.f, 0.f};

  const int srow   = t >> 3;
  const int schunk = ((t & 7) ^ (srow & 7)) << 4;
  const char* Ag = (const char*)xb;
  const char* Bg = (const char*)wb;

  auto stage = [&](int kt, int buf) {
    #pragma unroll
    for (int s = 0; s < 4; ++s) {
      const int r = s * 32 + srow;
      __builtin_amdgcn_global_load_lds(
          (const __attribute__((address_space(1))) unsigned int*)
              (Ag + (size_t)(m0 + r) * 1024 + kt * 128 + schunk),
          (__attribute__((address_space(3))) unsigned int*)
              (As + buf * 16384 + s * 4096 + w * 1024),
          16, 0, 0);
      __builtin_amdgcn_global_load_lds(
          (const __attribute__((address_space(1))) unsigned int*)
              (Bg + (size_t)(n0 + r) * 1024 + kt * 128 + schunk),
          (__attribute__((address_space(3))) unsigned int*)
              (Bs + buf * 16384 + s * 4096 + w * 1024),
          16, 0, 0);
    }
  };

  stage(0, 0);

  for (int kt = 0; kt < 8; ++kt) {
    const int cur = kt & 1;
    asm volatile("s_waitcnt vmcnt(0)");    // my tile-kt loads landed
    __builtin_amdgcn_s_barrier();          // all waves past compute(kt-1)
    __builtin_amdgcn_sched_barrier(0);
    if (kt < 7) stage(kt + 1, cur ^ 1);    // safe post-barrier

    const char* Al = As + cur * 16384;
    const char* Bl = Bs + cur * 16384;
    #pragma unroll
    for (int ks = 0; ks < 2; ++ks) {
      bf16x8 af[4], bfr[4];
      #pragma unroll
      for (int mt = 0; mt < 4; ++mt)
        af[mt] = *(const bf16x8*)(Al + (wm * 64 + mt * 16 + lo) * 128
                                  + (((ks * 4 + hi) ^ (lo & 7)) << 4));
      #pragma unroll
      for (int nt = 0; nt < 4; ++nt)
        bfr[nt] = *(const bf16x8*)(Bl + (wn * 64 + nt * 16 + lo) * 128
                                   + (((ks * 4 + hi) ^ (lo & 7)) << 4));
      #pragma unroll
      for (int mt = 0; mt < 4; ++mt)
        #pragma unroll
        for (int nt = 0; nt < 4; ++nt)
          acc[mt][nt] = __builtin_amdgcn_mfma_f32_16x16x32_bf16(
              af[mt], bfr[nt], acc[mt][nt], 0, 0, 0);
    }
    __builtin_amdgcn_sched_barrier(0);
  }

  const int nbase = n0 + wn * 64;
  const int typ   = nbase >> 9;
  const int hh    = (nbase >> 6) & 7;
  const int bb    = m0 >> 11;
  const int lbase = (m0 & 2047) + wm * 64;

  float bq[4];
  #pragma unroll
  for (int nt = 0; nt < 4; ++nt) bq[nt] = bias[nbase + nt * 16 + lo];
  #pragma unroll
  for (int mt = 0; mt < 4; ++mt)
    #pragma unroll
    for (int nt = 0; nt < 4; ++nt)
      #pragma unroll
      for (int reg = 0; reg < 4; ++reg) acc[mt][nt][reg] += bq[nt];

  if (typ == 2) {
    unsigned short* vbase = vt + (size_t)(bb * HDIM + hh) * DDIM * LDIM;
    #pragma unroll
    for (int mt = 0; mt < 4; ++mt)
      #pragma unroll
      for (int nt = 0; nt < 4; ++nt) {
        const int d = nt * 16 + lo;
        #pragma unroll
        for (int reg = 0; reg < 4; ++reg) {
          const int l = lbase + mt * 16 + hi * 4 + reg;
          vbase[(size_t)d * LDIM + l] = f2bf(acc[mt][nt][reg]);
        }
      }
  } else {
    unsigned short* dstb = (typ ? kb : qb) + (size_t)(bb * HDIM + hh) * LDIM * DDIM;
    #pragma unroll
    for (int mt = 0; mt < 4; ++mt)
      #pragma unroll
      for (int nt = 0; nt < 4; ++nt) {
        const int d   = nt * 16 + lo;
        const float sgn = (nt & 2) ? 1.f : -1.f;
        #pragma unroll
        for (int reg = 0; reg < 4; ++reg) {
          const int l = lbase + mt * 16 + hi * 4 + reg;
          const float c = cosT[l * 64 + d], s = sinT[l * 64 + d];
          const float v = acc[mt][nt][reg] * c + sgn * acc[mt][nt ^ 2][reg] * s;
          dstb[(size_t)l * DDIM + d] = f2bf(v);
        }
      }
  }
}

// ---------------------------------------------------------------------------
// Kernel 2: bf16 MFMA flash attention (round-15 kernel VERBATIM -- verified
// 51.1 us, absmax 1.22e-4; single-barrier loop, LDS-staged K/V, XCD swizzle).
// ---------------------------------------------------------------------------
#define CLOG2 0.18033688f          /* 0.125 * log2(e) */

__global__ __launch_bounds__(512, 4) void attn_kernel(
    unsigned short* __restrict__ qb, const unsigned short* __restrict__ kb,
    const unsigned short* __restrict__ vt) {
  __shared__ char Lds[65536];
  const int t    = threadIdx.x;
  const int w    = t >> 6, lane = t & 63;
  const int lo   = lane & 15, hi = lane >> 4;
  const int wq   = w & 3, half = w >> 2;
  const int flat = blockIdx.x;
  const int xcd  = flat & 7, jj = flat >> 3;        // jj in 0..63
  const int bh   = xcd + 8 * (jj >> 4);
  const int q0   = (jj & 15) * 128 + wq * 32;
  const int kb0  = half * 1024;

  const char* Kb = (const char*)kb + (size_t)bh * (LDIM * DDIM * 2);
  const char* Vb = (const char*)vt + (size_t)bh * (LDIM * DDIM * 2);
  unsigned short* Qb = qb + (size_t)bh * (LDIM * DDIM);

  bf16x8 qf[2][2];
  #pragma unroll
  for (int g = 0; g < 2; ++g)
    #pragma unroll
    for (int kd = 0; kd < 2; ++kd)
      qf[g][kd] = *(const bf16x8*)((const char*)(Qb + (size_t)(q0 + g * 16 + lo) * DDIM)
                                   + kd * 64 + hi * 16);

  f32x4 o[2][4];
  float mrun[2] = {0.f, 0.f}, mc[2] = {0.f, 0.f}, lpart[2] = {0.f, 0.f};
  #pragma unroll
  for (int g = 0; g < 2; ++g)
    #pragma unroll
    for (int r = 0; r < 4; ++r) o[g][r] = (f32x4){0.f, 0.f, 0.f, 0.f};

  const int krow = wq * 8 + (lane >> 3);
  const int kch  = ((lane & 7) ^ (krow & 7)) << 4;
  const int vrow = wq * 16 + (lane >> 2);
  const int vch  = ((lane & 3) ^ ((vrow >> 1) & 3)) << 4;

  auto stage = [&](int tile, int buf) {
    __builtin_amdgcn_global_load_lds(
        (const __attribute__((address_space(1))) unsigned int*)
            (Kb + (size_t)(kb0 + tile * 32 + krow) * 128 + kch),
        (__attribute__((address_space(3))) unsigned int*)
            (Lds + (half * 2 + buf) * 4096 + wq * 1024),
        16, 0, 0);
    __builtin_amdgcn_global_load_lds(
        (const __attribute__((address_space(1))) unsigned int*)
            (Vb + (size_t)vrow * (LDIM * 2) + (size_t)(kb0 + tile * 32) * 2 + vch),
        (__attribute__((address_space(3))) unsigned int*)
            (Lds + 16384 + (half * 2 + buf) * 4096 + wq * 1024),
        16, 0, 0);
  };

  stage(0, 0);

  char* Pwb = Lds + 32768 + w * 4096;

  for (int kt = 0; kt < 32; ++kt) {
    const int cur = kt & 1;
    asm volatile("s_waitcnt vmcnt(0)");     // my tile-kt loads landed
    __builtin_amdgcn_s_barrier();           // the ONLY barrier per iteration
    __builtin_amdgcn_sched_barrier(0);
    const int nk = kt < 31 ? kt + 1 : 31;   // last prefetch is a dummy
    stage(nk, cur ^ 1);                     // safe post-barrier

    const char* Kl = Lds + (half * 2 + cur) * 4096;
    const char* Vl = Lds + 16384 + (half * 2 + cur) * 4096;

    // ---- S^T = K Q ----
    f32x4 sv[2][2];
    __builtin_amdgcn_s_setprio(1);
    #pragma unroll
    for (int nt = 0; nt < 2; ++nt) {
      sv[0][nt] = (f32x4){0.f, 0.f, 0.f, 0.f};
      sv[1][nt] = (f32x4){0.f, 0.f, 0.f, 0.f};
      const int key = nt * 16 + lo;
      #pragma unroll
      for (int kd = 0; kd < 2; ++kd) {
        const bf16x8 kf = *(const bf16x8*)(Kl + key * 128
                            + (((kd * 4 + hi) ^ (key & 7)) << 4));
        sv[0][nt] = __builtin_amdgcn_mfma_f32_16x16x32_bf16(kf, qf[0][kd], sv[0][nt], 0, 0, 0);
        sv[1][nt] = __builtin_amdgcn_mfma_f32_16x16x32_bf16(kf, qf[1][kd], sv[1][nt], 0, 0, 0);
      }
    }
    __builtin_amdgcn_s_setprio(0);

    // ---- softmax per group: no max pass; pk_fma + raw v_exp_f32 ----
    #pragma unroll
    for (int g = 0; g < 2; ++g) {
      const float* sflat = (const float*)sv[g];
      const f32x2 cc2 = {CLOG2, CLOG2};
      const f32x2 mm2 = {-mc[g], -mc[g]};
      float pv[8];
      float ps = 0.f;
      #pragma unroll
      for (int i = 0; i < 4; ++i) {
        f32x2 a; a[0] = sflat[2*i]; a[1] = sflat[2*i+1];
        f32x2 xr;
        asm("v_pk_fma_f32 %0, %1, %2, %3" : "=v"(xr) : "v"(a), "v"(cc2), "v"(mm2));
        float p0, p1;
        asm("v_exp_f32 %0, %1" : "=v"(p0) : "v"(xr[0]));
        asm("v_exp_f32 %0, %1" : "=v"(p1) : "v"(xr[1]));
        pv[2*i] = p0; pv[2*i+1] = p1;
        ps += p0; ps += p1;
      }

      if (__builtin_expect((bool)__ballot(ps > 65536.f), 0)) {
        float mx = -1e30f;
        #pragma unroll
        for (int i = 0; i < 8; ++i) mx = fmaxf(mx, sflat[i]);
        mx = fmaxf(mx, __shfl_xor(mx, 16));
        mx = fmaxf(mx, __shfl_xor(mx, 32));
        const float newm = fmaxf(mrun[g], mx);
        const float al   = exp2f((mrun[g] - newm) * CLOG2);
        lpart[g] *= al;
        #pragma unroll
        for (int r = 0; r < 4; ++r) {
          const float aq = __shfl(al, (hi << 2) + r);
          #pragma unroll
          for (int dt = 0; dt < 4; ++dt) o[g][dt][r] *= aq;
        }
        mrun[g] = newm;
        mc[g]   = newm * CLOG2;
        ps = 0.f;
        #pragma unroll
        for (int i = 0; i < 8; ++i) {
          const float p = exp2f(fmaf(sflat[i], CLOG2, -mc[g]));
          pv[i] = p;
          ps += p;
        }
      }
      lpart[g] += ps;

      #pragma unroll
      for (int nt = 0; nt < 2; ++nt) {
        unsigned w0, w1;
        asm("v_cvt_pk_bf16_f32 %0, %1, %2"
            : "=v"(w0) : "v"(pv[nt*4+0]), "v"(pv[nt*4+1]));
        asm("v_cvt_pk_bf16_f32 %0, %1, %2"
            : "=v"(w1) : "v"(pv[nt*4+2]), "v"(pv[nt*4+3]));
        uint2 d2; d2.x = w0; d2.y = w1;
        *(uint2*)(Pwb + g * 2048 + lo * 128
                  + ((nt * 32 + hi * 8) ^ ((lo & 7) << 4))) = d2;
      }
    }

    // ---- O += P V (vf shared across both groups) ----
    __builtin_amdgcn_s_setprio(1);
    {
      const bf16x8 pf0 = *(const bf16x8*)(Pwb + lo * 128
                           + ((hi ^ (lo & 7)) << 4));
      const bf16x8 pf1 = *(const bf16x8*)(Pwb + 2048 + lo * 128
                           + ((hi ^ (lo & 7)) << 4));
      #pragma unroll
      for (int dt = 0; dt < 4; ++dt) {
        const int d = dt * 16 + lo;
        const bf16x8 vf = *(const bf16x8*)(Vl + d * 64
                            + ((hi ^ ((d >> 1) & 3)) << 4));
        o[0][dt] = __builtin_amdgcn_mfma_f32_16x16x32_bf16(pf0, vf, o[0][dt], 0, 0, 0);
        o[1][dt] = __builtin_amdgcn_mfma_f32_16x16x32_bf16(pf1, vf, o[1][dt], 0, 0, 0);
      }
    }
    __builtin_amdgcn_s_setprio(0);

    __builtin_amdgcn_sched_barrier(0);
  }

  // ---- epilogue: drain dummy prefetch, merge halves through LDS ----
  asm volatile("s_waitcnt vmcnt(0)");
  __syncthreads();

  float rs[2];
  #pragma unroll
  for (int g = 0; g < 2; ++g) {
    rs[g] = lpart[g];
    rs[g] += __shfl_xor(rs[g], 16);
    rs[g] += __shfl_xor(rs[g], 32);
  }

  if (half == 1) {
    #pragma unroll
    for (int g = 0; g < 2; ++g) {
      #pragma unroll
      for (int dt = 0; dt < 4; ++dt)
        #pragma unroll
        for (int r = 0; r < 4; ++r)
          *(float*)(Lds + wq * 8192
                    + ((g * 16 + hi * 4 + r) * 64 + dt * 16 + lo) * 4) = o[g][dt][r];
      if (hi == 0) {
        *(float*)(Lds + 32768 + wq * 256 + g * 64 + lo * 4)       = rs[g];
        *(float*)(Lds + 32768 + wq * 256 + 128 + g * 64 + lo * 4) = mrun[g];
      }
    }
  }
  __syncthreads();
  if (half == 0) {
    #pragma unroll
    for (int g = 0; g < 2; ++g)
      #pragma unroll
      for (int r = 0; r < 4; ++r) {
        const int qrow = hi * 4 + r;
        const float m_a = __shfl(mrun[g], qrow);
        const float l_a = __shfl(rs[g], qrow);
        const float l_b = *(const float*)(Lds + 32768 + wq * 256 + g * 64 + qrow * 4);
        const float m_b = *(const float*)(Lds + 32768 + wq * 256 + 128 + g * 64 + qrow * 4);
        const float m  = fmaxf(m_a, m_b);
        const float aa = exp2f((m_a - m) * CLOG2);
        const float ab = exp2f((m_b - m) * CLOG2);
        const float inv = 1.f / (l_a * aa + l_b * ab);
        const int q = q0 + g * 16 + qrow;
        #pragma unroll
        for (int dt = 0; dt < 4; ++dt) {
          const float ob = *(const float*)(Lds + wq * 8192
                            + ((g * 16 + qrow) * 64 + dt * 16 + lo) * 4);
          Qb[(size_t)q * DDIM + dt * 16 + lo] =
              f2bf((o[g][dt][r] * aa + ob * ab) * inv);
        }
      }
  }
}

// ---------------------------------------------------------------------------
// Kernel 3: out = attn_out @ proj_w^T + b via bf16 MFMA. 64x128 tile,
// XCD-swizzled 1D grid (512). NOW: double-buffered + single-barrier loop.
// ---------------------------------------------------------------------------
__global__ __launch_bounds__(256) void proj_gemm_kernel(
    const unsigned short* __restrict__ ab, const unsigned short* __restrict__ pwb,
    const float* __restrict__ bias, float* __restrict__ out) {
  __shared__ char As[16384];   // 2 x 8KB
  __shared__ char Bs[32768];   // 2 x 16KB
  const int t  = threadIdx.x;
  const int w  = t >> 6, lane = t & 63;
  const int lo = lane & 15, hi = lane >> 4;
  const int wm = w >> 1, wn = w & 1;
  const int flat = blockIdx.x;
  const int xcd = flat & 7, j = flat >> 3;          // j in 0..63
  const int m0 = (xcd + 8 * (j >> 2)) * 64;
  const int n0 = (j & 3) * 128;

  f32x4 acc[2][4];
  #pragma unroll
  for (int mt = 0; mt < 2; ++mt)
    #pragma unroll
    for (int nt = 0; nt < 4; ++nt) acc[mt][nt] = (f32x4){0.f, 0.f, 0.f, 0.f};

  const int srow   = t >> 3;
  const int schunk = ((t & 7) ^ (srow & 7)) << 4;
  const char* Ag = (const char*)ab;
  const char* Bg = (const char*)pwb;

  auto stage = [&](int kt, int buf) {
    const int hh = kt;
    #pragma unroll
    for (int s = 0; s < 2; ++s) {          // A: 64 rows
      const int r = s * 32 + srow;
      const int m = m0 + r;
      const int bb = m >> 11, l = m & 2047;
      __builtin_amdgcn_global_load_lds(
          (const __attribute__((address_space(1))) unsigned int*)
              (Ag + ((size_t)(bb * HDIM + hh) * LDIM + l) * 128 + schunk),
          (__attribute__((address_space(3))) unsigned int*)
              (As + buf * 8192 + s * 4096 + w * 1024),
          16, 0, 0);
    }
    #pragma unroll
    for (int s = 0; s < 4; ++s) {          // B: 128 rows
      const int r = s * 32 + srow;
      __builtin_amdgcn_global_load_lds(
          (const __attribute__((address_space(1))) unsigned int*)
              (Bg + (size_t)(n0 + r) * 1024 + kt * 128 + schunk),
          (__attribute__((address_space(3))) unsigned int*)
              (Bs + buf * 16384 + s * 4096 + w * 1024),
          16, 0, 0);
    }
  };

  stage(0, 0);

  for (int kt = 0; kt < 8; ++kt) {
    const int cur = kt & 1;
    asm volatile("s_waitcnt vmcnt(0)");
    __builtin_amdgcn_s_barrier();
    __builtin_amdgcn_sched_barrier(0);
    if (kt < 7) stage(kt + 1, cur ^ 1);

    const char* Al = As + cur * 8192;
    const char* Bl = Bs + cur * 16384;
    #pragma unroll
    for (int ks = 0; ks < 2; ++ks) {
      bf16x8 af[2], bfr[4];
      #pragma unroll
      for (int mt = 0; mt < 2; ++mt)
        af[mt] = *(const bf16x8*)(Al + (wm * 32 + mt * 16 + lo) * 128
                                  + (((ks * 4 + hi) ^ (lo & 7)) << 4));
      #pragma unroll
      for (int nt = 0; nt < 4; ++nt)
        bfr[nt] = *(const bf16x8*)(Bl + (wn * 64 + nt * 16 + lo) * 128
                                   + (((ks * 4 + hi) ^ (lo & 7)) << 4));
      #pragma unroll
      for (int mt = 0; mt < 2; ++mt)
        #pragma unroll
        for (int nt = 0; nt < 4; ++nt)
          acc[mt][nt] = __builtin_amdgcn_mfma_f32_16x16x32_bf16(
              af[mt], bfr[nt], acc[mt][nt], 0, 0, 0);
    }
    __builtin_amdgcn_sched_barrier(0);
  }

  const int nn = n0 + wn * 64;
  float bp[4];
  #pragma unroll
  for (int nt = 0; nt < 4; ++nt) bp[nt] = bias[nn + nt * 16 + lo];
  #pragma unroll
  for (int mt = 0; mt < 2; ++mt)
    #pragma unroll
    for (int nt = 0; nt < 4; ++nt)
      #pragma unroll
      for (int reg = 0; reg < 4; ++reg) {
        const int m = m0 + wm * 32 + mt * 16 + hi * 4 + reg;
        out[(size_t)m * CDIM + nn + nt * 16 + lo] = acc[mt][nt][reg] + bp[nt];
      }
}

// ---------------------------------------------------------------------------
extern "C" void kernel_launch(void* const* d_in, const int* in_sizes, int n_in,
                              void* d_out, int out_size, void* d_ws, size_t ws_size,
                              hipStream_t stream) {
  const float* x      = (const float*)d_in[0];
  const float* qkv_w  = (const float*)d_in[1];
  const float* qkv_b  = (const float*)d_in[2];
  const float* proj_w = (const float*)d_in[3];
  const float* proj_b = (const float*)d_in[4];
  const float* cosT   = (const float*)d_in[5];
  const float* sinT   = (const float*)d_in[6];
  float* out = (float*)d_out;

  // ws layout (u16): qb 8MB | kb 8MB | vt 8MB | xb 8MB | wb 1.5MB | pwb 0.5MB
  unsigned short* qb  = (unsigned short*)d_ws;
  unsigned short* kb  = qb + (size_t)BDIM * HDIM * LDIM * DDIM;
  unsigned short* vt  = kb + (size_t)BDIM * HDIM * LDIM * DDIM;
  unsigned short* xb  = vt + (size_t)BDIM * HDIM * LDIM * DDIM;
  unsigned short* wb  = xb + (size_t)BDIM * LDIM * CDIM;
  unsigned short* pwb = wb + (size_t)3 * CDIM * CDIM;

  // 0) fp32 -> bf16 conversions (x + both weights)
  convert_kernel<<<dim3(2560), 256, 0, stream>>>(x, qkv_w, proj_w, xb, wb, pwb);
  // 1) QKV GEMM (bf16 MFMA, dbuf single-barrier) + fused RoPE + scatter
  qkv_gemm_kernel<<<dim3(768), 256, 0, stream>>>(xb, wb, qkv_b, cosT, sinT,
                                                 qb, kb, vt);
  // 2) bf16 MFMA flash attention (round-15 verbatim, verified)
  attn_kernel<<<dim3(512), 512, 0, stream>>>(qb, kb, vt);
  // 3) output projection (dbuf single-barrier, XCD-swizzled)
  proj_gemm_kernel<<<dim3(512), 256, 0, stream>>>(qb, pwb, proj_b, out);
}